// Round 17
// baseline (168.106 us; speedup 1.0000x reference)
//
#include <hip/hip_runtime.h>
#include <math.h>

#define BB 32
#define NN 8400
#define MM 32
#define NC 80
#define PD 85
#define TOPK 10
#define CAPG 768            // per-(b,g) candidate cap (binomial mean 295, +27 sigma)
#define KPL 12              // CAPG / 64 register slots per lane
#define NBLK 1050           // BB*NN / 256 exactly
#define FLT_BIG 3.4e38f

__device__ __forceinline__ float bcef_(float x, float t) {
    return fmaxf(x, 0.0f) - x * t + log1pf(expf(-fabsf(x)));
}

// fast hardware-native helpers: v_exp/v_log/v_rcp/v_sqrt, ~1-2 ulp
__device__ __forceinline__ float frcp_(float x)  { return __builtin_amdgcn_rcpf(x); }
__device__ __forceinline__ float fsqrt_(float x) { return __builtin_amdgcn_sqrtf(x); }
__device__ __forceinline__ float fsig_(float x)  { return frcp_(1.0f + __expf(-x)); }

// shared by kC and kD so matched-gt argmin sees bit-consistent costs
__device__ __forceinline__ float iou_(float4 pb, float gx1, float gy1,
                                      float gx2, float gy2, float ga) {
    float ix1 = fmaxf(gx1, pb.x), iy1 = fmaxf(gy1, pb.y);
    float ix2 = fminf(gx2, pb.z), iy2 = fminf(gy2, pb.w);
    float inter = fmaxf(ix2 - ix1, 0.0f) * fmaxf(iy2 - iy1, 0.0f);
    float pa = fmaxf(pb.z - pb.x, 0.0f) * fmaxf(pb.w - pb.y, 0.0f);
    float uni = ga + pa - inter + 1e-7f;
    return inter * frcp_(uni);
}
__device__ __forceinline__ float cost_(float cl, float so_n, float base_n, float iou) {
    float s = fsqrt_(fsig_(cl) * so_n);
    float lp = __logf(s + 1e-7f);
    float lq = __logf(1.0f - s + 1e-7f);
    return base_n - lp + lq - 3.0f * __logf(iou + 1e-8f);
}

// ---- Kernel A: per-row precompute + in-box bitmask (round-15 proven) ------
// Also zeroes the last-block `done` counter (workspace is poisoned 0xAA).
__global__ void __launch_bounds__(256) kA(const float* __restrict__ pred,
                                          const float* __restrict__ tgt,
                                          float4* __restrict__ pxyxy,
                                          float* __restrict__ base,
                                          float* __restrict__ so,
                                          float* __restrict__ objlogit,
                                          unsigned int* __restrict__ inmask,
                                          unsigned int* __restrict__ mask,
                                          int* __restrict__ done) {
    const int tid = threadIdx.x;
    const int lane = tid & 63, wid = tid >> 6;
    const int rs = lane >> 5, g = lane & 31;
    const int b = blockIdx.y;
    const int tile = blockIdx.x;             // 525 tiles of 16 rows

    if (tile == 0 && b == 0 && tid == 255) *done = 0;

    const float* t = tgt + ((size_t)b * MM + g) * 5;
    const float gx1 = t[1] - t[3] * 0.5f, gy1 = t[2] - t[4] * 0.5f;
    const float gx2 = t[1] + t[3] * 0.5f, gy2 = t[2] + t[4] * 0.5f;

    for (int itr = 0; itr < 2; ++itr) {
        const int pl = wid * 2 + itr;        // pair-local 0..7
        const int r0 = tile * 16 + pl * 2;   // global row (even)
        const size_t off = ((size_t)b * NN + r0) * PD;

        float x0 = pred[off + lane];                     // pos 0..63 (coalesced)
        float x1 = pred[off + 64 + lane];                // pos 64..127 (coalesced)

        float cx0 = __shfl(x0, 0), cy0 = __shfl(x0, 1), w0 = __shfl(x0, 2), h0 = __shfl(x0, 3), ol0 = __shfl(x0, 4);
        float cx1 = __shfl(x1, 21), cy1 = __shfl(x1, 22), w1 = __shfl(x1, 23), h1 = __shfl(x1, 24), ol1 = __shfl(x1, 25);
        float so0 = fsig_(ol0), so1 = fsig_(ol1);

        // in-box ballot (lanes 0-31: row0 x g; lanes 32-63: row1 x g)
        const float cxs = rs ? cx1 : cx0, cys = rs ? cy1 : cy0;
        const bool inb = (cxs > gx1) && (cxs < gx2) && (cys > gy1) && (cys < gy2);
        const unsigned long long bal = __ballot(inb);
        const bool r0a = (bal & 0xFFFFFFFFull) != 0ull;
        const bool r1a = (bal >> 32) != 0ull;

        // per-row small outputs from registers
        const size_t gi = (size_t)b * NN + r0;
        if (lane == 0) {
            pxyxy[gi] = make_float4(cx0 - w0 * 0.5f, cy0 - h0 * 0.5f,
                                    cx0 + w0 * 0.5f, cy0 + h0 * 0.5f);
            objlogit[gi] = ol0; so[gi] = so0;
        } else if (lane == 1) {
            pxyxy[gi + 1] = make_float4(cx1 - w1 * 0.5f, cy1 - h1 * 0.5f,
                                        cx1 + w1 * 0.5f, cy1 + h1 * 0.5f);
            objlogit[gi + 1] = ol1; so[gi + 1] = so1;
        } else if (lane == 2) mask[gi] = 0u;             // fold memset in
        else if (lane == 3) mask[gi + 1] = 0u;
        else if (lane == 4) inmask[gi] = (unsigned int)(bal & 0xFFFFFFFFull);
        else if (lane == 5) inmask[gi + 1] = (unsigned int)(bal >> 32);

        if (r0a) {   // row0 class sum: pos 5..84 = x0(lane>=5) + x1(lane<21)
            float a0 = 0.0f;
            if (lane >= 5)  a0 += __logf(1.0f - fsqrt_(fsig_(x0) * so0) + 1e-7f);
            if (lane < 21)  a0 += __logf(1.0f - fsqrt_(fsig_(x1) * so0) + 1e-7f);
            #pragma unroll
            for (int o = 32; o; o >>= 1) a0 += __shfl_xor(a0, o);
            if (lane == 0) base[gi] = -a0;
        }
        if (r1a) {   // row1 class sum: pos 90..169 = x1(lane>=26) + x2(lane<42)
            float x2 = (lane < 42) ? pred[off + 128 + lane] : 0.0f;
            float a1 = 0.0f;
            if (lane >= 26) a1 += __logf(1.0f - fsqrt_(fsig_(x1) * so1) + 1e-7f);
            if (lane < 42)  a1 += __logf(1.0f - fsqrt_(fsig_(x2) * so1) + 1e-7f);
            #pragma unroll
            for (int o = 32; o; o >>= 1) a1 += __shfl_xor(a1, o);
            if (lane == 0) base[gi + 1] = -a1;
        }
    }
}

// ---- Kernel C: bitmask scan -> LDS compaction -> IN-REGISTER selection ----
// (round-15 proven, verbatim). Multiset-deterministic selection; cnt<10
// zero-pads the iou sum bit-identically; p>=cnt assigns nothing.
__global__ void __launch_bounds__(256) kC(const float* __restrict__ pred,
                                          const float* __restrict__ tgt,
                                          const float4* __restrict__ pxyxy,
                                          const float* __restrict__ base,
                                          const float* __restrict__ so,
                                          const unsigned int* __restrict__ inmask,
                                          unsigned int* __restrict__ mask) {
    // remap so an image's 32 g-blocks share an XCD (L2 locality for gathers)
    const int x_ = blockIdx.x & 7, k_ = blockIdx.x >> 3;
    const int g = k_ & 31, b = ((k_ >> 5) << 3) | x_;
    const int tid = threadIdx.x;
    const int wid = tid >> 6, lane = tid & 63;

    const float* t = tgt + ((size_t)b * MM + g) * 5;
    const int gcls = (int)t[0];
    const float gx1 = t[1] - t[3] * 0.5f, gy1 = t[2] - t[4] * 0.5f;
    const float gx2 = t[1] + t[3] * 0.5f, gy2 = t[2] + t[4] * 0.5f;
    const float ga = fmaxf(gx2 - gx1, 0.0f) * fmaxf(gy2 - gy1, 0.0f);
    const size_t nb = (size_t)b * NN;
    const unsigned int gbit = 1u << g;

    __shared__ float s_iou[CAPG];
    __shared__ float s_cost[CAPG];
    __shared__ int   s_n[CAPG];
    __shared__ int   s_cnt;
    if (tid == 0) s_cnt = 0;
    __syncthreads();

    for (int n = tid; n < NN; n += 256) {
        if (inmask[nb + n] & gbit) {         // execz-skip for inactive waves
            float4 pb = pxyxy[nb + n];
            float iou = iou_(pb, gx1, gy1, gx2, gy2, ga);
            float cl = pred[(nb + (size_t)n) * PD + 5 + gcls];
            float co = cost_(cl, so[nb + n], base[nb + n], iou);
            int idx = atomicAdd(&s_cnt, 1);
            if (idx < CAPG) { s_iou[idx] = iou; s_cost[idx] = co; s_n[idx] = n; }
        }
    }
    __syncthreads();

    if (wid != 0) return;                    // wave 0 finishes alone
    const int cnt = min(s_cnt, CAPG);

    // LDS -> registers (static indexing; pads are neutral elements)
    float riou[KPL], rcost[KPL]; int rn[KPL];
    #pragma unroll
    for (int k = 0; k < KPL; ++k) {
        int i = lane + 64 * k;
        bool v = i < cnt;
        riou[k]  = v ? s_iou[i]  : -1.0f;
        rcost[k] = v ? s_cost[i] : FLT_BIG;
        rn[k]    = v ? s_n[i]    : 0x7fffffff;
    }

    // Phase 1: sum of top-10 ious, descending add order
    float ssum = 0.0f;
    {
        const int lim = (cnt < TOPK) ? cnt : TOPK;
        for (int p = 0; p < lim; ++p) {
            float bv = -1.0f; int bidx = 0x7fffffff;
            #pragma unroll
            for (int k = 0; k < KPL; ++k)
                if (riou[k] > bv) { bv = riou[k]; bidx = lane + 64 * k; }
            #pragma unroll
            for (int o = 32; o; o >>= 1) {
                float ov = __shfl_xor(bv, o); int oi = __shfl_xor(bidx, o);
                if (ov > bv || (ov == bv && oi < bidx)) { bv = ov; bidx = oi; }
            }
            ssum += bv;                      // uniform after reduce
            if ((bidx & 63) == lane) {       // consume (static unrolled index)
                int kk = bidx >> 6;
                #pragma unroll
                for (int k = 0; k < KPL; ++k) if (k == kk) riou[k] = -1.0f;
            }
        }
    }
    int dynk = (int)ssum;                    // trunc toward zero, sum in [0,10)
    if (dynk < 1) dynk = 1;
    if (dynk > TOPK) dynk = TOPK;

    // Phase 2: dyn_k lexicographically-smallest (cost, n) -> assignment bits
    {
        const int lim = (cnt < dynk) ? cnt : dynk;
        for (int p = 0; p < lim; ++p) {
            float bv = FLT_BIG; int bn_ = 0x7fffffff; int bidx = -1;
            #pragma unroll
            for (int k = 0; k < KPL; ++k)
                if (rcost[k] < bv || (rcost[k] == bv && rn[k] < bn_)) {
                    bv = rcost[k]; bn_ = rn[k]; bidx = lane + 64 * k;
                }
            #pragma unroll
            for (int o = 32; o; o >>= 1) {
                float ov = __shfl_xor(bv, o);
                int on = __shfl_xor(bn_, o);
                int oi = __shfl_xor(bidx, o);
                if (ov < bv || (ov == bv && on < bn_)) { bv = ov; bn_ = on; bidx = oi; }
            }
            if ((bidx & 63) == lane) {       // consume
                int kk = bidx >> 6;
                #pragma unroll
                for (int k = 0; k < KPL; ++k)
                    if (k == kk) { rcost[k] = FLT_BIG; rn[k] = 0x7fffffff; }
            }
            if (lane == 0) atomicOr(&mask[nb + bn_], gbit);
        }
    }
}

// ---- Kernel DE: per-pred losses + fused last-block final reduction --------
// kD body verbatim (round-15 proven). The final kE reduction is executed by
// the LAST block to finish (threadfence + atomic ticket), in the SAME fixed
// order kE used -> bit-identical, deterministic. `done` reset for next replay.
__global__ void __launch_bounds__(256) kDE(const float* __restrict__ pred,
                   const float* __restrict__ tgt,
                   const float4* __restrict__ pxyxy,
                   const float* __restrict__ base,
                   const float* __restrict__ so,
                   const float* __restrict__ objlogit,
                   const unsigned int* __restrict__ mask,
                   float* __restrict__ partials,
                   int* __restrict__ done,
                   float* __restrict__ out) {
    const int tid = threadIdx.x;
    const int i0 = blockIdx.x * 256;
    const int i = i0 + tid;                 // BB*NN == 1050*256 exactly
    const int lane = tid & 63, wid = tid >> 6;
    const int b = i / NN;

    float obj_l, cls_l = 0.0f, reg_l = 0.0f, nfg = 0.0f;
    const unsigned int mk = mask[i];
    obj_l = bcef_(objlogit[i], mk ? 1.0f : 0.0f);

    __shared__ int s_list[256];
    __shared__ int s_gcls[256];
    __shared__ int s_wbase[4];
    __shared__ int s_cnt;

    unsigned long long bal = __ballot(mk != 0);
    int wpos = __popcll(bal & ((1ull << lane) - 1ull));
    if (lane == 0) s_wbase[wid] = __popcll(bal);
    __syncthreads();
    if (tid == 0) {
        int acc = 0;
        for (int w = 0; w < 4; ++w) { int t_ = s_wbase[w]; s_wbase[w] = acc; acc += t_; }
        s_cnt = acc;
    }
    __syncthreads();

    if (mk) {
        int e = s_wbase[wid] + wpos;
        s_list[e] = tid;
        nfg = 1.0f;
        float4 pb = pxyxy[i];
        float base_n = base[i], so_n = so[i];
        float best = 3.0e30f; int bg = 0;
        for (int g = 0; g < MM; ++g) {
            if ((mk >> g) & 1u) {
                const float* tg = tgt + ((size_t)b * MM + g) * 5;
                float ggx1 = tg[1] - tg[3] * 0.5f, ggy1 = tg[2] - tg[4] * 0.5f;
                float ggx2 = tg[1] + tg[3] * 0.5f, ggy2 = tg[2] + tg[4] * 0.5f;
                float gga = fmaxf(ggx2 - ggx1, 0.0f) * fmaxf(ggy2 - ggy1, 0.0f);
                float iou = iou_(pb, ggx1, ggy1, ggx2, ggy2, gga);
                float cl = pred[(size_t)i * PD + 5 + (int)tg[0]];
                float cvv = cost_(cl, so_n, base_n, iou);
                if (cvv < best) { best = cvv; bg = g; }
            }
        }
        const float* tm = tgt + ((size_t)b * MM + bg) * 5;
        s_gcls[e] = (int)tm[0];
        float px1 = pb.x, py1 = pb.y, px2 = pb.z, py2 = pb.w;
        float tx1 = tm[1] - tm[3] * 0.5f, ty1 = tm[2] - tm[4] * 0.5f;
        float tx2 = tm[1] + tm[3] * 0.5f, ty2 = tm[2] + tm[4] * 0.5f;
        float ix1 = fmaxf(px1, tx1), iy1 = fmaxf(py1, ty1);
        float ix2 = fminf(px2, tx2), iy2 = fminf(py2, ty2);
        float inter = fmaxf(ix2 - ix1, 0.0f) * fmaxf(iy2 - iy1, 0.0f);
        float pa = fmaxf(px2 - px1, 0.0f) * fmaxf(py2 - py1, 0.0f);
        float ta = fmaxf(tx2 - tx1, 0.0f) * fmaxf(ty2 - ty1, 0.0f);
        float uni = pa + ta - inter + 1e-7f;
        float iou = inter / uni;
        float ex1 = fminf(px1, tx1), ey1 = fminf(py1, ty1);
        float ex2 = fmaxf(px2, tx2), ey2 = fmaxf(py2, ty2);
        float enclose = (ex2 - ex1) * (ey2 - ey1) + 1e-7f;
        float giou = iou - (enclose - uni) / enclose;
        reg_l = 1.0f - giou;
    }
    __syncthreads();

    const int cnt = s_cnt;
    const int nitems = cnt * NC;
    for (int item = tid; item < nitems; item += 256) {
        int e = item / NC;
        int c = item - e * NC;
        int gi = i0 + s_list[e];
        float x = pred[(size_t)gi * PD + 5 + c];
        cls_l += bcef_(x, (c == s_gcls[e]) ? 1.0f : 0.0f);
    }

    __shared__ float red[256];
    float sums[4] = {cls_l, obj_l, reg_l, nfg};
    float out4[4];
    for (int j = 0; j < 4; ++j) {
        red[tid] = sums[j];
        __syncthreads();
        for (int off = 128; off > 0; off >>= 1) {
            if (tid < off) red[tid] += red[tid + off];
            __syncthreads();
        }
        out4[j] = red[0];
        __syncthreads();
    }
    if (tid == 0) {
        float* pr = partials + (size_t)blockIdx.x * 4;
        pr[0] = out4[0]; pr[1] = out4[1]; pr[2] = out4[2]; pr[3] = out4[3];
    }

    // ---- fused kE: last block performs the fixed-order final reduction ----
    __shared__ int s_last;
    __threadfence();                         // publish partials (device scope)
    if (tid == 0) s_last = (atomicAdd(done, 1) == NBLK - 1) ? 1 : 0;
    __syncthreads();
    if (s_last) {
        __threadfence();                     // acquire all blocks' partials
        float s[4] = {0, 0, 0, 0};
        for (int k = tid; k < NBLK; k += 256) {
            s[0] += partials[(size_t)k * 4 + 0];
            s[1] += partials[(size_t)k * 4 + 1];
            s[2] += partials[(size_t)k * 4 + 2];
            s[3] += partials[(size_t)k * 4 + 3];
        }
        float tot[4];
        for (int j = 0; j < 4; ++j) {
            red[tid] = s[j];
            __syncthreads();
            for (int off = 128; off > 0; off >>= 1) {
                if (tid < off) red[tid] += red[tid + off];
                __syncthreads();
            }
            tot[j] = red[0];
            __syncthreads();
        }
        if (tid == 0) {
            float nfg_t = fmaxf(tot[3], 1.0f);
            out[0] = (tot[0] + tot[1] + 5.0f * tot[2]) / nfg_t;
            *done = 0;                       // reset for next graph replay
        }
    }
}

extern "C" void kernel_launch(void* const* d_in, const int* in_sizes, int n_in,
                              void* d_out, int out_size, void* d_ws, size_t ws_size,
                              hipStream_t stream) {
    const float* pred = (const float*)d_in[0];   // (B, N, 85) f32
    const float* tgt  = (const float*)d_in[1];   // (B, M, 5)  f32
    float* out = (float*)d_out;

    // Workspace layout (~11 MB)
    char* ws = (char*)d_ws;
    size_t off = 0;
    float4* pxyxy = (float4*)(ws + off);            off += (size_t)BB * NN * sizeof(float4);
    float* base = (float*)(ws + off);               off += (size_t)BB * NN * sizeof(float);
    float* so = (float*)(ws + off);                 off += (size_t)BB * NN * sizeof(float);
    float* objlogit = (float*)(ws + off);           off += (size_t)BB * NN * sizeof(float);
    unsigned int* inmask = (unsigned int*)(ws + off); off += (size_t)BB * NN * sizeof(unsigned int);
    unsigned int* mask = (unsigned int*)(ws + off); off += (size_t)BB * NN * sizeof(unsigned int);
    float* partials = (float*)(ws + off);           off += (size_t)NBLK * 4 * sizeof(float);
    int* done = (int*)(ws + off);                   off += sizeof(int);

    dim3 gA(NN / 16, BB);                    // 525 x 32; zeroes mask + done
    kA<<<gA, 256, 0, stream>>>(pred, tgt, pxyxy, base, so, objlogit, inmask, mask, done);

    kC<<<MM * BB, 256, 0, stream>>>(pred, tgt, pxyxy, base, so, inmask, mask);

    kDE<<<NBLK, 256, 0, stream>>>(pred, tgt, pxyxy, base, so, objlogit, mask,
                                  partials, done, out);
}

// Round 18
// 85.377 us; speedup vs baseline: 1.9690x; 1.9690x over previous
//
#include <hip/hip_runtime.h>
#include <math.h>

#define BB 32
#define NN 8400
#define MM 32
#define NC 80
#define PD 85
#define TOPK 10
#define CAPG 768            // per-(b,g) candidate cap (binomial mean 295, +27 sigma)
#define KPL 12              // CAPG / 64 register slots per lane
#define NBLK 1050           // BB*NN / 256 exactly
#define FLT_BIG 3.4e38f

// fast hardware-native helpers: v_exp/v_log/v_rcp/v_sqrt, ~1-2 ulp
__device__ __forceinline__ float frcp_(float x)  { return __builtin_amdgcn_rcpf(x); }
__device__ __forceinline__ float fsqrt_(float x) { return __builtin_amdgcn_sqrtf(x); }
__device__ __forceinline__ float fsig_(float x)  { return frcp_(1.0f + __expf(-x)); }

// fast BCE (2-ulp transcendentals; relative err ~1e-7 on each term, sums are
// ~1e5 -> abs err ~0.02 << 2.5 threshold)
__device__ __forceinline__ float bcef_(float x, float t) {
    return fmaxf(x, 0.0f) - x * t + __logf(1.0f + __expf(-fabsf(x)));
}

// shared by kC and kD so matched-gt argmin sees bit-consistent costs
__device__ __forceinline__ float iou_(float4 pb, float gx1, float gy1,
                                      float gx2, float gy2, float ga) {
    float ix1 = fmaxf(gx1, pb.x), iy1 = fmaxf(gy1, pb.y);
    float ix2 = fminf(gx2, pb.z), iy2 = fminf(gy2, pb.w);
    float inter = fmaxf(ix2 - ix1, 0.0f) * fmaxf(iy2 - iy1, 0.0f);
    float pa = fmaxf(pb.z - pb.x, 0.0f) * fmaxf(pb.w - pb.y, 0.0f);
    float uni = ga + pa - inter + 1e-7f;
    return inter * frcp_(uni);
}
__device__ __forceinline__ float cost_(float cl, float so_n, float base_n, float iou) {
    float s = fsqrt_(fsig_(cl) * so_n);
    float lp = __logf(s + 1e-7f);
    float lq = __logf(1.0f - s + 1e-7f);
    return base_n - lp + lq - 3.0f * __logf(iou + 1e-8f);
}

// ---- Kernel A: per-row precompute + in-box bitmask (round-15 proven) ------
__global__ void __launch_bounds__(256) kA(const float* __restrict__ pred,
                                          const float* __restrict__ tgt,
                                          float4* __restrict__ pxyxy,
                                          float* __restrict__ base,
                                          float* __restrict__ so,
                                          float* __restrict__ objlogit,
                                          unsigned int* __restrict__ inmask,
                                          unsigned int* __restrict__ mask) {
    const int tid = threadIdx.x;
    const int lane = tid & 63, wid = tid >> 6;
    const int rs = lane >> 5, g = lane & 31;
    const int b = blockIdx.y;
    const int tile = blockIdx.x;             // 525 tiles of 16 rows

    const float* t = tgt + ((size_t)b * MM + g) * 5;
    const float gx1 = t[1] - t[3] * 0.5f, gy1 = t[2] - t[4] * 0.5f;
    const float gx2 = t[1] + t[3] * 0.5f, gy2 = t[2] + t[4] * 0.5f;

    for (int itr = 0; itr < 2; ++itr) {
        const int pl = wid * 2 + itr;        // pair-local 0..7
        const int r0 = tile * 16 + pl * 2;   // global row (even)
        const size_t off = ((size_t)b * NN + r0) * PD;

        float x0 = pred[off + lane];                     // pos 0..63 (coalesced)
        float x1 = pred[off + 64 + lane];                // pos 64..127 (coalesced)

        float cx0 = __shfl(x0, 0), cy0 = __shfl(x0, 1), w0 = __shfl(x0, 2), h0 = __shfl(x0, 3), ol0 = __shfl(x0, 4);
        float cx1 = __shfl(x1, 21), cy1 = __shfl(x1, 22), w1 = __shfl(x1, 23), h1 = __shfl(x1, 24), ol1 = __shfl(x1, 25);
        float so0 = fsig_(ol0), so1 = fsig_(ol1);

        // in-box ballot (lanes 0-31: row0 x g; lanes 32-63: row1 x g)
        const float cxs = rs ? cx1 : cx0, cys = rs ? cy1 : cy0;
        const bool inb = (cxs > gx1) && (cxs < gx2) && (cys > gy1) && (cys < gy2);
        const unsigned long long bal = __ballot(inb);
        const bool r0a = (bal & 0xFFFFFFFFull) != 0ull;
        const bool r1a = (bal >> 32) != 0ull;

        // per-row small outputs from registers
        const size_t gi = (size_t)b * NN + r0;
        if (lane == 0) {
            pxyxy[gi] = make_float4(cx0 - w0 * 0.5f, cy0 - h0 * 0.5f,
                                    cx0 + w0 * 0.5f, cy0 + h0 * 0.5f);
            objlogit[gi] = ol0; so[gi] = so0;
        } else if (lane == 1) {
            pxyxy[gi + 1] = make_float4(cx1 - w1 * 0.5f, cy1 - h1 * 0.5f,
                                        cx1 + w1 * 0.5f, cy1 + h1 * 0.5f);
            objlogit[gi + 1] = ol1; so[gi + 1] = so1;
        } else if (lane == 2) mask[gi] = 0u;             // fold memset in
        else if (lane == 3) mask[gi + 1] = 0u;
        else if (lane == 4) inmask[gi] = (unsigned int)(bal & 0xFFFFFFFFull);
        else if (lane == 5) inmask[gi + 1] = (unsigned int)(bal >> 32);

        if (r0a) {   // row0 class sum: pos 5..84 = x0(lane>=5) + x1(lane<21)
            float a0 = 0.0f;
            if (lane >= 5)  a0 += __logf(1.0f - fsqrt_(fsig_(x0) * so0) + 1e-7f);
            if (lane < 21)  a0 += __logf(1.0f - fsqrt_(fsig_(x1) * so0) + 1e-7f);
            #pragma unroll
            for (int o = 32; o; o >>= 1) a0 += __shfl_xor(a0, o);
            if (lane == 0) base[gi] = -a0;
        }
        if (r1a) {   // row1 class sum: pos 90..169 = x1(lane>=26) + x2(lane<42)
            float x2 = (lane < 42) ? pred[off + 128 + lane] : 0.0f;
            float a1 = 0.0f;
            if (lane >= 26) a1 += __logf(1.0f - fsqrt_(fsig_(x1) * so1) + 1e-7f);
            if (lane < 42)  a1 += __logf(1.0f - fsqrt_(fsig_(x2) * so1) + 1e-7f);
            #pragma unroll
            for (int o = 32; o; o >>= 1) a1 += __shfl_xor(a1, o);
            if (lane == 0) base[gi + 1] = -a1;
        }
    }
}

// ---- Kernel C: 4-way-prefetched bitmask scan -> LDS compaction -> register
// selection (round-15 proven selection verbatim). The 4 independent inmask
// loads issue together, cutting the scan's exposed latency chain ~4x.
__global__ void __launch_bounds__(256) kC(const float* __restrict__ pred,
                                          const float* __restrict__ tgt,
                                          const float4* __restrict__ pxyxy,
                                          const float* __restrict__ base,
                                          const float* __restrict__ so,
                                          const unsigned int* __restrict__ inmask,
                                          unsigned int* __restrict__ mask) {
    // remap so an image's 32 g-blocks share an XCD (L2 locality for gathers)
    const int x_ = blockIdx.x & 7, k_ = blockIdx.x >> 3;
    const int g = k_ & 31, b = ((k_ >> 5) << 3) | x_;
    const int tid = threadIdx.x;
    const int wid = tid >> 6, lane = tid & 63;

    const float* t = tgt + ((size_t)b * MM + g) * 5;
    const int gcls = (int)t[0];
    const float gx1 = t[1] - t[3] * 0.5f, gy1 = t[2] - t[4] * 0.5f;
    const float gx2 = t[1] + t[3] * 0.5f, gy2 = t[2] + t[4] * 0.5f;
    const float ga = fmaxf(gx2 - gx1, 0.0f) * fmaxf(gy2 - gy1, 0.0f);
    const size_t nb = (size_t)b * NN;
    const unsigned int gbit = 1u << g;

    __shared__ float s_iou[CAPG];
    __shared__ float s_cost[CAPG];
    __shared__ int   s_n[CAPG];
    __shared__ int   s_cnt;
    if (tid == 0) s_cnt = 0;
    __syncthreads();

    #define KC_BODY(nn_)                                                       \
        do { int n = (nn_);                                                    \
            float4 pb = pxyxy[nb + n];                                         \
            float iou = iou_(pb, gx1, gy1, gx2, gy2, ga);                      \
            float cl = pred[(nb + (size_t)n) * PD + 5 + gcls];                 \
            float co = cost_(cl, so[nb + n], base[nb + n], iou);               \
            int idx = atomicAdd(&s_cnt, 1);                                    \
            if (idx < CAPG) { s_iou[idx] = iou; s_cost[idx] = co; s_n[idx] = n; } \
        } while (0)

    for (int n4 = tid; n4 < NN; n4 += 1024) {
        unsigned int m0 = inmask[nb + n4];
        unsigned int m1 = (n4 + 256 < NN) ? inmask[nb + n4 + 256] : 0u;
        unsigned int m2 = (n4 + 512 < NN) ? inmask[nb + n4 + 512] : 0u;
        unsigned int m3 = (n4 + 768 < NN) ? inmask[nb + n4 + 768] : 0u;
        if (m0 & gbit) KC_BODY(n4);
        if (m1 & gbit) KC_BODY(n4 + 256);
        if (m2 & gbit) KC_BODY(n4 + 512);
        if (m3 & gbit) KC_BODY(n4 + 768);
    }
    #undef KC_BODY
    __syncthreads();

    if (wid != 0) return;                    // wave 0 finishes alone
    const int cnt = min(s_cnt, CAPG);

    // LDS -> registers (static indexing; pads are neutral elements)
    float riou[KPL], rcost[KPL]; int rn[KPL];
    #pragma unroll
    for (int k = 0; k < KPL; ++k) {
        int i = lane + 64 * k;
        bool v = i < cnt;
        riou[k]  = v ? s_iou[i]  : -1.0f;
        rcost[k] = v ? s_cost[i] : FLT_BIG;
        rn[k]    = v ? s_n[i]    : 0x7fffffff;
    }

    // Phase 1: sum of top-10 ious, descending add order
    float ssum = 0.0f;
    {
        const int lim = (cnt < TOPK) ? cnt : TOPK;
        for (int p = 0; p < lim; ++p) {
            float bv = -1.0f; int bidx = 0x7fffffff;
            #pragma unroll
            for (int k = 0; k < KPL; ++k)
                if (riou[k] > bv) { bv = riou[k]; bidx = lane + 64 * k; }
            #pragma unroll
            for (int o = 32; o; o >>= 1) {
                float ov = __shfl_xor(bv, o); int oi = __shfl_xor(bidx, o);
                if (ov > bv || (ov == bv && oi < bidx)) { bv = ov; bidx = oi; }
            }
            ssum += bv;                      // uniform after reduce
            if ((bidx & 63) == lane) {       // consume (static unrolled index)
                int kk = bidx >> 6;
                #pragma unroll
                for (int k = 0; k < KPL; ++k) if (k == kk) riou[k] = -1.0f;
            }
        }
    }
    int dynk = (int)ssum;                    // trunc toward zero, sum in [0,10)
    if (dynk < 1) dynk = 1;
    if (dynk > TOPK) dynk = TOPK;

    // Phase 2: dyn_k lexicographically-smallest (cost, n) -> assignment bits
    {
        const int lim = (cnt < dynk) ? cnt : dynk;
        for (int p = 0; p < lim; ++p) {
            float bv = FLT_BIG; int bn_ = 0x7fffffff; int bidx = -1;
            #pragma unroll
            for (int k = 0; k < KPL; ++k)
                if (rcost[k] < bv || (rcost[k] == bv && rn[k] < bn_)) {
                    bv = rcost[k]; bn_ = rn[k]; bidx = lane + 64 * k;
                }
            #pragma unroll
            for (int o = 32; o; o >>= 1) {
                float ov = __shfl_xor(bv, o);
                int on = __shfl_xor(bn_, o);
                int oi = __shfl_xor(bidx, o);
                if (ov < bv || (ov == bv && on < bn_)) { bv = ov; bn_ = on; bidx = oi; }
            }
            if ((bidx & 63) == lane) {       // consume
                int kk = bidx >> 6;
                #pragma unroll
                for (int k = 0; k < KPL; ++k)
                    if (k == kk) { rcost[k] = FLT_BIG; rn[k] = 0x7fffffff; }
            }
            if (lane == 0) atomicOr(&mask[nb + bn_], gbit);
        }
    }
}

// ---- Kernel D: compacted fg, fast-math BCE, shuffle reduction -------------
__global__ void __launch_bounds__(256) kD(const float* __restrict__ pred,
                   const float* __restrict__ tgt,
                   const float4* __restrict__ pxyxy,
                   const float* __restrict__ base,
                   const float* __restrict__ so,
                   const float* __restrict__ objlogit,
                   const unsigned int* __restrict__ mask,
                   float* __restrict__ partials) {
    const int tid = threadIdx.x;
    const int i0 = blockIdx.x * 256;
    const int i = i0 + tid;                 // BB*NN == 1050*256 exactly
    const int lane = tid & 63, wid = tid >> 6;
    const int b = i / NN;

    float obj_l, cls_l = 0.0f, reg_l = 0.0f, nfg = 0.0f;
    const unsigned int mk = mask[i];
    obj_l = bcef_(objlogit[i], mk ? 1.0f : 0.0f);

    __shared__ int s_list[256];
    __shared__ int s_gcls[256];
    __shared__ int s_wbase[4];
    __shared__ int s_cnt;

    unsigned long long bal = __ballot(mk != 0);
    int wpos = __popcll(bal & ((1ull << lane) - 1ull));
    if (lane == 0) s_wbase[wid] = __popcll(bal);
    __syncthreads();
    if (tid == 0) {
        int acc = 0;
        for (int w = 0; w < 4; ++w) { int t_ = s_wbase[w]; s_wbase[w] = acc; acc += t_; }
        s_cnt = acc;
    }
    __syncthreads();

    if (mk) {
        int e = s_wbase[wid] + wpos;
        s_list[e] = tid;
        nfg = 1.0f;
        float4 pb = pxyxy[i];
        float base_n = base[i], so_n = so[i];
        // matched gt: first-min over set bits (ffs walk, ascending g)
        float best = 3.0e30f; int bg = 0;
        unsigned int m = mk;
        while (m) {
            int g = __ffs(m) - 1;
            m &= m - 1;
            const float* tg = tgt + ((size_t)b * MM + g) * 5;
            float ggx1 = tg[1] - tg[3] * 0.5f, ggy1 = tg[2] - tg[4] * 0.5f;
            float ggx2 = tg[1] + tg[3] * 0.5f, ggy2 = tg[2] + tg[4] * 0.5f;
            float gga = fmaxf(ggx2 - ggx1, 0.0f) * fmaxf(ggy2 - ggy1, 0.0f);
            float iou = iou_(pb, ggx1, ggy1, ggx2, ggy2, gga);
            float cl = pred[(size_t)i * PD + 5 + (int)tg[0]];
            float cvv = cost_(cl, so_n, base_n, iou);
            if (cvv < best) { best = cvv; bg = g; }
        }
        const float* tm = tgt + ((size_t)b * MM + bg) * 5;
        s_gcls[e] = (int)tm[0];
        float px1 = pb.x, py1 = pb.y, px2 = pb.z, py2 = pb.w;
        float tx1 = tm[1] - tm[3] * 0.5f, ty1 = tm[2] - tm[4] * 0.5f;
        float tx2 = tm[1] + tm[3] * 0.5f, ty2 = tm[2] + tm[4] * 0.5f;
        float ix1 = fmaxf(px1, tx1), iy1 = fmaxf(py1, ty1);
        float ix2 = fminf(px2, tx2), iy2 = fminf(py2, ty2);
        float inter = fmaxf(ix2 - ix1, 0.0f) * fmaxf(iy2 - iy1, 0.0f);
        float pa = fmaxf(px2 - px1, 0.0f) * fmaxf(py2 - py1, 0.0f);
        float ta = fmaxf(tx2 - tx1, 0.0f) * fmaxf(ty2 - ty1, 0.0f);
        float uni = pa + ta - inter + 1e-7f;
        float iou = inter / uni;
        float ex1 = fminf(px1, tx1), ey1 = fminf(py1, ty1);
        float ex2 = fmaxf(px2, tx2), ey2 = fmaxf(py2, ty2);
        float enclose = (ex2 - ex1) * (ey2 - ey1) + 1e-7f;
        float giou = iou - (enclose - uni) / enclose;
        reg_l = 1.0f - giou;
    }
    __syncthreads();

    const int cnt = s_cnt;
    const int nitems = cnt * NC;
    for (int item = tid; item < nitems; item += 256) {
        int e = item / NC;
        int c = item - e * NC;
        int gi = i0 + s_list[e];
        float x = pred[(size_t)gi * PD + 5 + c];
        cls_l += bcef_(x, (c == s_gcls[e]) ? 1.0f : 0.0f);
    }

    // wave shuffle reduce (fixed order) + one LDS stage; deterministic
    float sums[4] = {cls_l, obj_l, reg_l, nfg};
    #pragma unroll
    for (int j = 0; j < 4; ++j)
        #pragma unroll
        for (int o = 32; o; o >>= 1) sums[j] += __shfl_xor(sums[j], o);
    __shared__ float sred[16];               // [wave][j]
    if (lane == 0) {
        sred[wid * 4 + 0] = sums[0]; sred[wid * 4 + 1] = sums[1];
        sred[wid * 4 + 2] = sums[2]; sred[wid * 4 + 3] = sums[3];
    }
    __syncthreads();
    if (tid == 0) {
        float* pr = partials + (size_t)blockIdx.x * 4;
        #pragma unroll
        for (int j = 0; j < 4; ++j)
            pr[j] = sred[j] + sred[4 + j] + sred[8 + j] + sred[12 + j];
    }
}

// ---- Kernel E: final deterministic reduction -----------------------------
__global__ void kE(const float* __restrict__ partials, int nblk, float* __restrict__ out) {
    __shared__ float red[256];
    float s[4] = {0, 0, 0, 0};
    for (int i = threadIdx.x; i < nblk; i += 256) {
        s[0] += partials[(size_t)i * 4 + 0];
        s[1] += partials[(size_t)i * 4 + 1];
        s[2] += partials[(size_t)i * 4 + 2];
        s[3] += partials[(size_t)i * 4 + 3];
    }
    float tot[4];
    for (int j = 0; j < 4; ++j) {
        red[threadIdx.x] = s[j];
        __syncthreads();
        for (int off = 128; off > 0; off >>= 1) {
            if (threadIdx.x < off) red[threadIdx.x] += red[threadIdx.x + off];
            __syncthreads();
        }
        tot[j] = red[0];
        __syncthreads();
    }
    if (threadIdx.x == 0) {
        float nfg = fmaxf(tot[3], 1.0f);
        out[0] = (tot[0] + tot[1] + 5.0f * tot[2]) / nfg;
    }
}

extern "C" void kernel_launch(void* const* d_in, const int* in_sizes, int n_in,
                              void* d_out, int out_size, void* d_ws, size_t ws_size,
                              hipStream_t stream) {
    const float* pred = (const float*)d_in[0];   // (B, N, 85) f32
    const float* tgt  = (const float*)d_in[1];   // (B, M, 5)  f32
    float* out = (float*)d_out;

    // Workspace layout (~11 MB)
    char* ws = (char*)d_ws;
    size_t off = 0;
    float4* pxyxy = (float4*)(ws + off);            off += (size_t)BB * NN * sizeof(float4);
    float* base = (float*)(ws + off);               off += (size_t)BB * NN * sizeof(float);
    float* so = (float*)(ws + off);                 off += (size_t)BB * NN * sizeof(float);
    float* objlogit = (float*)(ws + off);           off += (size_t)BB * NN * sizeof(float);
    unsigned int* inmask = (unsigned int*)(ws + off); off += (size_t)BB * NN * sizeof(unsigned int);
    unsigned int* mask = (unsigned int*)(ws + off); off += (size_t)BB * NN * sizeof(unsigned int);
    float* partials = (float*)(ws + off);           off += (size_t)NBLK * 4 * sizeof(float);

    dim3 gA(NN / 16, BB);                    // 525 x 32; zeroes mask internally
    kA<<<gA, 256, 0, stream>>>(pred, tgt, pxyxy, base, so, objlogit, inmask, mask);

    kC<<<MM * BB, 256, 0, stream>>>(pred, tgt, pxyxy, base, so, inmask, mask);

    kD<<<NBLK, 256, 0, stream>>>(pred, tgt, pxyxy, base, so, objlogit, mask, partials);

    kE<<<1, 256, 0, stream>>>(partials, NBLK, out);
}

// Round 19
// 82.891 us; speedup vs baseline: 2.0280x; 1.0300x over previous
//
#include <hip/hip_runtime.h>
#include <math.h>

#define BB 32
#define NN 8400
#define MM 32
#define NC 80
#define PD 85
#define TOPK 10
#define CAPG 768            // per-(b,g) candidate cap (binomial mean 295, +27 sigma)
#define KPL 12              // CAPG / 64 register slots per lane
#define NBLK 1050           // BB*NN / 256 exactly
#define FLT_BIG 3.4e38f

// fast hardware-native helpers: v_exp/v_log/v_rcp/v_sqrt, ~1-2 ulp
__device__ __forceinline__ float frcp_(float x)  { return __builtin_amdgcn_rcpf(x); }
__device__ __forceinline__ float fsqrt_(float x) { return __builtin_amdgcn_sqrtf(x); }
__device__ __forceinline__ float fsig_(float x)  { return frcp_(1.0f + __expf(-x)); }

// fast BCE (2-ulp transcendentals; relative err ~1e-7 on each term)
__device__ __forceinline__ float bcef_(float x, float t) {
    return fmaxf(x, 0.0f) - x * t + __logf(1.0f + __expf(-fabsf(x)));
}

// shared by kC and kD so matched-gt argmin sees bit-consistent costs
__device__ __forceinline__ float iou_(float4 pb, float gx1, float gy1,
                                      float gx2, float gy2, float ga) {
    float ix1 = fmaxf(gx1, pb.x), iy1 = fmaxf(gy1, pb.y);
    float ix2 = fminf(gx2, pb.z), iy2 = fminf(gy2, pb.w);
    float inter = fmaxf(ix2 - ix1, 0.0f) * fmaxf(iy2 - iy1, 0.0f);
    float pa = fmaxf(pb.z - pb.x, 0.0f) * fmaxf(pb.w - pb.y, 0.0f);
    float uni = ga + pa - inter + 1e-7f;
    return inter * frcp_(uni);
}
__device__ __forceinline__ float cost_(float cl, float so_n, float base_n, float iou) {
    float s = fsqrt_(fsig_(cl) * so_n);
    float lp = __logf(s + 1e-7f);
    float lq = __logf(1.0f - s + 1e-7f);
    return base_n - lp + lq - 3.0f * __logf(iou + 1e-8f);
}

// ---- Kernel A: thread-per-row header pass + wave-per-active-row class sums
// Phase 1: each thread loads its row's 20B header (one independent gather),
// tests 32 LDS GT boxes -> inmask in-register, writes pxyxy/objlogit/so/
// inmask/mask coalesced across consecutive rows.
// Phase 2: ballot-compacted active rows (~32%); one row per wave iteration
// with the proven lane->term mapping (lane>=5 from x0, lane<21 from x1).
__global__ void __launch_bounds__(256) kA(const float* __restrict__ pred,
                                          const float* __restrict__ tgt,
                                          float4* __restrict__ pxyxy,
                                          float* __restrict__ base,
                                          float* __restrict__ so,
                                          float* __restrict__ objlogit,
                                          unsigned int* __restrict__ inmask,
                                          unsigned int* __restrict__ mask) {
    const int tid = threadIdx.x;
    const int lane = tid & 63, wid = tid >> 6;
    const int b = blockIdx.y;
    const int r = blockIdx.x * 256 + tid;    // this thread's row

    __shared__ float4 sg[MM];                // GT boxes (xyxy)
    __shared__ int s_act[256];
    __shared__ int s_wb[4];
    __shared__ int s_na;

    if (tid < MM) {
        const float* t = tgt + ((size_t)b * MM + tid) * 5;
        sg[tid] = make_float4(t[1] - t[3] * 0.5f, t[2] - t[4] * 0.5f,
                              t[1] + t[3] * 0.5f, t[2] + t[4] * 0.5f);
    }
    __syncthreads();

    const bool valid = r < NN;
    unsigned int im = 0u;
    if (valid) {
        const size_t gi = (size_t)b * NN + r;
        const float* p = pred + gi * PD;
        float4 h4 = *reinterpret_cast<const float4*>(p);   // cx, cy, w, h
        float ol = p[4];
        float cx = h4.x, cy = h4.y, w = h4.z, h = h4.w;
        #pragma unroll
        for (int g = 0; g < MM; ++g) {
            float4 gb = sg[g];               // LDS broadcast (uniform addr)
            bool inb = (cx > gb.x) && (cx < gb.z) && (cy > gb.y) && (cy < gb.w);
            im |= inb ? (1u << g) : 0u;
        }
        pxyxy[gi] = make_float4(cx - w * 0.5f, cy - h * 0.5f,
                                cx + w * 0.5f, cy + h * 0.5f);
        objlogit[gi] = ol;
        so[gi] = fsig_(ol);
        inmask[gi] = im;
        mask[gi] = 0u;                       // fold memset in
    }

    // deterministic compaction of active rows (im != 0)
    unsigned long long bal = __ballot(valid && im != 0u);
    int wpos = __popcll(bal & ((1ull << lane) - 1ull));
    if (lane == 0) s_wb[wid] = __popcll(bal);
    __syncthreads();
    if (tid == 0) {
        int acc = 0;
        for (int w2 = 0; w2 < 4; ++w2) { int t2 = s_wb[w2]; s_wb[w2] = acc; acc += t2; }
        s_na = acc;
    }
    __syncthreads();
    if (valid && im != 0u) s_act[s_wb[wid] + wpos] = r;
    __syncthreads();

    // phase 2: class-sum `base` for active rows, one row per wave iteration
    const int na = s_na;
    for (int idx = wid; idx < na; idx += 4) {
        const int ar = s_act[idx];
        const size_t off = ((size_t)b * NN + ar) * PD;
        float x0 = pred[off + lane];                            // pos 0..63
        float x1 = (lane < 21) ? pred[off + 64 + lane] : 0.0f;  // pos 64..84
        float so_r = fsig_(__shfl(x0, 4));                      // ol at pos 4
        float a = 0.0f;
        if (lane >= 5) a += __logf(1.0f - fsqrt_(fsig_(x0) * so_r) + 1e-7f); // c=lane-5
        if (lane < 21) a += __logf(1.0f - fsqrt_(fsig_(x1) * so_r) + 1e-7f); // c=59+lane
        #pragma unroll
        for (int o = 32; o; o >>= 1) a += __shfl_xor(a, o);
        if (lane == 0) base[(size_t)b * NN + ar] = -a;
    }
}

// ---- Kernel C: 4-way-prefetched bitmask scan -> LDS compaction -> register
// selection (round-18 proven, verbatim).
__global__ void __launch_bounds__(256) kC(const float* __restrict__ pred,
                                          const float* __restrict__ tgt,
                                          const float4* __restrict__ pxyxy,
                                          const float* __restrict__ base,
                                          const float* __restrict__ so,
                                          const unsigned int* __restrict__ inmask,
                                          unsigned int* __restrict__ mask) {
    // remap so an image's 32 g-blocks share an XCD (L2 locality for gathers)
    const int x_ = blockIdx.x & 7, k_ = blockIdx.x >> 3;
    const int g = k_ & 31, b = ((k_ >> 5) << 3) | x_;
    const int tid = threadIdx.x;
    const int wid = tid >> 6, lane = tid & 63;

    const float* t = tgt + ((size_t)b * MM + g) * 5;
    const int gcls = (int)t[0];
    const float gx1 = t[1] - t[3] * 0.5f, gy1 = t[2] - t[4] * 0.5f;
    const float gx2 = t[1] + t[3] * 0.5f, gy2 = t[2] + t[4] * 0.5f;
    const float ga = fmaxf(gx2 - gx1, 0.0f) * fmaxf(gy2 - gy1, 0.0f);
    const size_t nb = (size_t)b * NN;
    const unsigned int gbit = 1u << g;

    __shared__ float s_iou[CAPG];
    __shared__ float s_cost[CAPG];
    __shared__ int   s_n[CAPG];
    __shared__ int   s_cnt;
    if (tid == 0) s_cnt = 0;
    __syncthreads();

    #define KC_BODY(nn_)                                                       \
        do { int n = (nn_);                                                    \
            float4 pb = pxyxy[nb + n];                                         \
            float iou = iou_(pb, gx1, gy1, gx2, gy2, ga);                      \
            float cl = pred[(nb + (size_t)n) * PD + 5 + gcls];                 \
            float co = cost_(cl, so[nb + n], base[nb + n], iou);               \
            int idx = atomicAdd(&s_cnt, 1);                                    \
            if (idx < CAPG) { s_iou[idx] = iou; s_cost[idx] = co; s_n[idx] = n; } \
        } while (0)

    for (int n4 = tid; n4 < NN; n4 += 1024) {
        unsigned int m0 = inmask[nb + n4];
        unsigned int m1 = (n4 + 256 < NN) ? inmask[nb + n4 + 256] : 0u;
        unsigned int m2 = (n4 + 512 < NN) ? inmask[nb + n4 + 512] : 0u;
        unsigned int m3 = (n4 + 768 < NN) ? inmask[nb + n4 + 768] : 0u;
        if (m0 & gbit) KC_BODY(n4);
        if (m1 & gbit) KC_BODY(n4 + 256);
        if (m2 & gbit) KC_BODY(n4 + 512);
        if (m3 & gbit) KC_BODY(n4 + 768);
    }
    #undef KC_BODY
    __syncthreads();

    if (wid != 0) return;                    // wave 0 finishes alone
    const int cnt = min(s_cnt, CAPG);

    // LDS -> registers (static indexing; pads are neutral elements)
    float riou[KPL], rcost[KPL]; int rn[KPL];
    #pragma unroll
    for (int k = 0; k < KPL; ++k) {
        int i = lane + 64 * k;
        bool v = i < cnt;
        riou[k]  = v ? s_iou[i]  : -1.0f;
        rcost[k] = v ? s_cost[i] : FLT_BIG;
        rn[k]    = v ? s_n[i]    : 0x7fffffff;
    }

    // Phase 1: sum of top-10 ious, descending add order
    float ssum = 0.0f;
    {
        const int lim = (cnt < TOPK) ? cnt : TOPK;
        for (int p = 0; p < lim; ++p) {
            float bv = -1.0f; int bidx = 0x7fffffff;
            #pragma unroll
            for (int k = 0; k < KPL; ++k)
                if (riou[k] > bv) { bv = riou[k]; bidx = lane + 64 * k; }
            #pragma unroll
            for (int o = 32; o; o >>= 1) {
                float ov = __shfl_xor(bv, o); int oi = __shfl_xor(bidx, o);
                if (ov > bv || (ov == bv && oi < bidx)) { bv = ov; bidx = oi; }
            }
            ssum += bv;                      // uniform after reduce
            if ((bidx & 63) == lane) {       // consume (static unrolled index)
                int kk = bidx >> 6;
                #pragma unroll
                for (int k = 0; k < KPL; ++k) if (k == kk) riou[k] = -1.0f;
            }
        }
    }
    int dynk = (int)ssum;                    // trunc toward zero, sum in [0,10)
    if (dynk < 1) dynk = 1;
    if (dynk > TOPK) dynk = TOPK;

    // Phase 2: dyn_k lexicographically-smallest (cost, n) -> assignment bits
    {
        const int lim = (cnt < dynk) ? cnt : dynk;
        for (int p = 0; p < lim; ++p) {
            float bv = FLT_BIG; int bn_ = 0x7fffffff; int bidx = -1;
            #pragma unroll
            for (int k = 0; k < KPL; ++k)
                if (rcost[k] < bv || (rcost[k] == bv && rn[k] < bn_)) {
                    bv = rcost[k]; bn_ = rn[k]; bidx = lane + 64 * k;
                }
            #pragma unroll
            for (int o = 32; o; o >>= 1) {
                float ov = __shfl_xor(bv, o);
                int on = __shfl_xor(bn_, o);
                int oi = __shfl_xor(bidx, o);
                if (ov < bv || (ov == bv && on < bn_)) { bv = ov; bn_ = on; bidx = oi; }
            }
            if ((bidx & 63) == lane) {       // consume
                int kk = bidx >> 6;
                #pragma unroll
                for (int k = 0; k < KPL; ++k)
                    if (k == kk) { rcost[k] = FLT_BIG; rn[k] = 0x7fffffff; }
            }
            if (lane == 0) atomicOr(&mask[nb + bn_], gbit);
        }
    }
}

// ---- Kernel D: compacted fg, fast-math BCE, shuffle reduction (R18 proven)
__global__ void __launch_bounds__(256) kD(const float* __restrict__ pred,
                   const float* __restrict__ tgt,
                   const float4* __restrict__ pxyxy,
                   const float* __restrict__ base,
                   const float* __restrict__ so,
                   const float* __restrict__ objlogit,
                   const unsigned int* __restrict__ mask,
                   float* __restrict__ partials) {
    const int tid = threadIdx.x;
    const int i0 = blockIdx.x * 256;
    const int i = i0 + tid;                 // BB*NN == 1050*256 exactly
    const int lane = tid & 63, wid = tid >> 6;
    const int b = i / NN;

    float obj_l, cls_l = 0.0f, reg_l = 0.0f, nfg = 0.0f;
    const unsigned int mk = mask[i];
    obj_l = bcef_(objlogit[i], mk ? 1.0f : 0.0f);

    __shared__ int s_list[256];
    __shared__ int s_gcls[256];
    __shared__ int s_wbase[4];
    __shared__ int s_cnt;

    unsigned long long bal = __ballot(mk != 0);
    int wpos = __popcll(bal & ((1ull << lane) - 1ull));
    if (lane == 0) s_wbase[wid] = __popcll(bal);
    __syncthreads();
    if (tid == 0) {
        int acc = 0;
        for (int w = 0; w < 4; ++w) { int t_ = s_wbase[w]; s_wbase[w] = acc; acc += t_; }
        s_cnt = acc;
    }
    __syncthreads();

    if (mk) {
        int e = s_wbase[wid] + wpos;
        s_list[e] = tid;
        nfg = 1.0f;
        float4 pb = pxyxy[i];
        float base_n = base[i], so_n = so[i];
        float best = 3.0e30f; int bg = 0;
        unsigned int m = mk;
        while (m) {
            int g = __ffs(m) - 1;
            m &= m - 1;
            const float* tg = tgt + ((size_t)b * MM + g) * 5;
            float ggx1 = tg[1] - tg[3] * 0.5f, ggy1 = tg[2] - tg[4] * 0.5f;
            float ggx2 = tg[1] + tg[3] * 0.5f, ggy2 = tg[2] + tg[4] * 0.5f;
            float gga = fmaxf(ggx2 - ggx1, 0.0f) * fmaxf(ggy2 - ggy1, 0.0f);
            float iou = iou_(pb, ggx1, ggy1, ggx2, ggy2, gga);
            float cl = pred[(size_t)i * PD + 5 + (int)tg[0]];
            float cvv = cost_(cl, so_n, base_n, iou);
            if (cvv < best) { best = cvv; bg = g; }
        }
        const float* tm = tgt + ((size_t)b * MM + bg) * 5;
        s_gcls[e] = (int)tm[0];
        float px1 = pb.x, py1 = pb.y, px2 = pb.z, py2 = pb.w;
        float tx1 = tm[1] - tm[3] * 0.5f, ty1 = tm[2] - tm[4] * 0.5f;
        float tx2 = tm[1] + tm[3] * 0.5f, ty2 = tm[2] + tm[4] * 0.5f;
        float ix1 = fmaxf(px1, tx1), iy1 = fmaxf(py1, ty1);
        float ix2 = fminf(px2, tx2), iy2 = fminf(py2, ty2);
        float inter = fmaxf(ix2 - ix1, 0.0f) * fmaxf(iy2 - iy1, 0.0f);
        float pa = fmaxf(px2 - px1, 0.0f) * fmaxf(py2 - py1, 0.0f);
        float ta = fmaxf(tx2 - tx1, 0.0f) * fmaxf(ty2 - ty1, 0.0f);
        float uni = pa + ta - inter + 1e-7f;
        float iou = inter / uni;
        float ex1 = fminf(px1, tx1), ey1 = fminf(py1, ty1);
        float ex2 = fmaxf(px2, tx2), ey2 = fmaxf(py2, ty2);
        float enclose = (ex2 - ex1) * (ey2 - ey1) + 1e-7f;
        float giou = iou - (enclose - uni) / enclose;
        reg_l = 1.0f - giou;
    }
    __syncthreads();

    const int cnt = s_cnt;
    const int nitems = cnt * NC;
    for (int item = tid; item < nitems; item += 256) {
        int e = item / NC;
        int c = item - e * NC;
        int gi = i0 + s_list[e];
        float x = pred[(size_t)gi * PD + 5 + c];
        cls_l += bcef_(x, (c == s_gcls[e]) ? 1.0f : 0.0f);
    }

    // wave shuffle reduce (fixed order) + one LDS stage; deterministic
    float sums[4] = {cls_l, obj_l, reg_l, nfg};
    #pragma unroll
    for (int j = 0; j < 4; ++j)
        #pragma unroll
        for (int o = 32; o; o >>= 1) sums[j] += __shfl_xor(sums[j], o);
    __shared__ float sred[16];               // [wave][j]
    if (lane == 0) {
        sred[wid * 4 + 0] = sums[0]; sred[wid * 4 + 1] = sums[1];
        sred[wid * 4 + 2] = sums[2]; sred[wid * 4 + 3] = sums[3];
    }
    __syncthreads();
    if (tid == 0) {
        float* pr = partials + (size_t)blockIdx.x * 4;
        #pragma unroll
        for (int j = 0; j < 4; ++j)
            pr[j] = sred[j] + sred[4 + j] + sred[8 + j] + sred[12 + j];
    }
}

// ---- Kernel E: final deterministic reduction -----------------------------
__global__ void kE(const float* __restrict__ partials, int nblk, float* __restrict__ out) {
    __shared__ float red[256];
    float s[4] = {0, 0, 0, 0};
    for (int i = threadIdx.x; i < nblk; i += 256) {
        s[0] += partials[(size_t)i * 4 + 0];
        s[1] += partials[(size_t)i * 4 + 1];
        s[2] += partials[(size_t)i * 4 + 2];
        s[3] += partials[(size_t)i * 4 + 3];
    }
    float tot[4];
    for (int j = 0; j < 4; ++j) {
        red[threadIdx.x] = s[j];
        __syncthreads();
        for (int off = 128; off > 0; off >>= 1) {
            if (threadIdx.x < off) red[threadIdx.x] += red[threadIdx.x + off];
            __syncthreads();
        }
        tot[j] = red[0];
        __syncthreads();
    }
    if (threadIdx.x == 0) {
        float nfg = fmaxf(tot[3], 1.0f);
        out[0] = (tot[0] + tot[1] + 5.0f * tot[2]) / nfg;
    }
}

extern "C" void kernel_launch(void* const* d_in, const int* in_sizes, int n_in,
                              void* d_out, int out_size, void* d_ws, size_t ws_size,
                              hipStream_t stream) {
    const float* pred = (const float*)d_in[0];   // (B, N, 85) f32
    const float* tgt  = (const float*)d_in[1];   // (B, M, 5)  f32
    float* out = (float*)d_out;

    // Workspace layout (~11 MB)
    char* ws = (char*)d_ws;
    size_t off = 0;
    float4* pxyxy = (float4*)(ws + off);            off += (size_t)BB * NN * sizeof(float4);
    float* base = (float*)(ws + off);               off += (size_t)BB * NN * sizeof(float);
    float* so = (float*)(ws + off);                 off += (size_t)BB * NN * sizeof(float);
    float* objlogit = (float*)(ws + off);           off += (size_t)BB * NN * sizeof(float);
    unsigned int* inmask = (unsigned int*)(ws + off); off += (size_t)BB * NN * sizeof(unsigned int);
    unsigned int* mask = (unsigned int*)(ws + off); off += (size_t)BB * NN * sizeof(unsigned int);
    float* partials = (float*)(ws + off);           off += (size_t)NBLK * 4 * sizeof(float);

    dim3 gA((NN + 255) / 256, BB);           // 33 x 32; zeroes mask internally
    kA<<<gA, 256, 0, stream>>>(pred, tgt, pxyxy, base, so, objlogit, inmask, mask);

    kC<<<MM * BB, 256, 0, stream>>>(pred, tgt, pxyxy, base, so, inmask, mask);

    kD<<<NBLK, 256, 0, stream>>>(pred, tgt, pxyxy, base, so, objlogit, mask, partials);

    kE<<<1, 256, 0, stream>>>(partials, NBLK, out);
}